// Round 6
// baseline (1645.105 us; speedup 1.0000x reference)
//
#include <hip/hip_runtime.h>
#include <cstdint>
#include <cstddef>

typedef _Float16 f16;
typedef _Float16 half2_t __attribute__((ext_vector_type(2)));
typedef _Float16 half4_t __attribute__((ext_vector_type(4)));
typedef _Float16 half8_t __attribute__((ext_vector_type(8)));
typedef float floatx4 __attribute__((ext_vector_type(4)));

__device__ __forceinline__ float fdot2u(uint32_t w, uint32_t h, float acc) {
#if __has_builtin(__builtin_amdgcn_fdot2)
    return __builtin_amdgcn_fdot2(__builtin_bit_cast(half2_t, w),
                                  __builtin_bit_cast(half2_t, h), acc, false);
#else
    half2_t a = __builtin_bit_cast(half2_t, w);
    half2_t b = __builtin_bit_cast(half2_t, h);
    return acc + (float)a[0] * (float)b[0] + (float)a[1] * (float)b[1];
#endif
}

// ---------------- fp32 -> f16 conversion ----------------
__global__ void cvt_kernel(const float* __restrict__ in, f16* __restrict__ out, int n4) {
    int i = blockIdx.x * blockDim.x + threadIdx.x;
    int stride = gridDim.x * blockDim.x;
    const float4* in4 = (const float4*)in;
    half4_t* out4 = (half4_t*)out;
    for (; i < n4; i += stride) {
        float4 v = in4[i];
        half4_t h = {(f16)v.x, (f16)v.y, (f16)v.z, (f16)v.w};
        out4[i] = h;
    }
}

// ---------------- bias sum ----------------
__global__ void bsum_kernel(const float* __restrict__ a, const float* __restrict__ b,
                            float* __restrict__ o) {
    int i = threadIdx.x;
    o[i] = a[i] + b[i];
}

// ---------------- pack W for the 512-thread matvec core ----------------
// Thread tid (0..511): kg = tid>>6 (k-group of 64), jq = tid&63 (j = 8*jq + r, r in [0,8)).
// k = kg*64 + c*8 + 2q (+parity), c in [0,8) (k-chunk of 8), q in [0,4) (k-pair).
// idx = c*32 + r*4 + q in [0,256).
// idx < 224 (c<7): register-resident, layout wp[idx*512 + tid]  (coalesced dword loads)
// c == 7: LDS-resident, layout wp[224*512 + (r*512 + tid)*4 + q]  (uint4 per (r,tid))
__global__ void pack_whh(const float* __restrict__ W, uint32_t* __restrict__ wp) {
    int id = blockIdx.x * 256 + threadIdx.x;   // 131072 = 512*256 pairs
    int j = id >> 8;        // 0..511
    int kp = id & 255;      // 0..255
    int k = kp * 2;
    int jq = j >> 3, r = j & 7;
    int kg = k >> 6;
    int c = (k >> 3) & 7;
    int q = (k >> 1) & 3;
    int tid = kg * 64 + jq;
    int idx = c * 32 + r * 4 + q;
    uint32_t lo = (uint32_t)__builtin_bit_cast(uint16_t, (f16)W[(size_t)j * 512 + k]);
    uint32_t hi = (uint32_t)__builtin_bit_cast(uint16_t, (f16)W[(size_t)j * 512 + k + 1]);
    size_t off;
    if (idx < 224) off = (size_t)idx * 512 + tid;
    else           off = (size_t)224 * 512 + ((size_t)(r * 512 + tid)) * 4 + q;
    wp[off] = (hi << 16) | lo;
}

// ---------------- xproj GEMM (proven) ----------------
__global__ __launch_bounds__(256) void gemm_xp(const f16* __restrict__ A,
                                               const f16* __restrict__ Bw,
                                               const float* __restrict__ bias,
                                               f16* __restrict__ C) {
    const int bn = blockIdx.x & 3;
    const int bm = blockIdx.x >> 2;
    const int tid = threadIdx.x;
    const int w = tid >> 6, l = tid & 63;
    const int wr = w >> 1, wc = w & 1;
    __shared__ f16 As[128 * 32];
    __shared__ f16 Bs[128 * 32];
    floatx4 acc[4][4] = {};
    const int lr = l & 15, lk = (l >> 4) * 8;
    for (int kk = 0; kk < 512; kk += 32) {
        __syncthreads();
        uint4 av[2], bv[2];
#pragma unroll
        for (int s = 0; s < 2; ++s) {
            int chunk = tid + s * 256;
            int row = chunk >> 2;
            int colh = (chunk & 3) * 8;
            av[s] = *(const uint4*)&A[((size_t)(bm * 128 + row)) * 512 + kk + colh];
            bv[s] = *(const uint4*)&Bw[((size_t)(bn * 128 + row)) * 512 + kk + colh];
        }
#pragma unroll
        for (int s = 0; s < 2; ++s) {
            int chunk = tid + s * 256;
            *(uint4*)&As[chunk * 8] = av[s];
            *(uint4*)&Bs[chunk * 8] = bv[s];
        }
        __syncthreads();
        half8_t af[4], bf[4];
#pragma unroll
        for (int m = 0; m < 4; ++m)
            af[m] = *(const half8_t*)&As[(wr * 64 + m * 16 + lr) * 32 + lk];
#pragma unroll
        for (int n = 0; n < 4; ++n)
            bf[n] = *(const half8_t*)&Bs[(wc * 64 + n * 16 + lr) * 32 + lk];
#pragma unroll
        for (int m = 0; m < 4; ++m)
#pragma unroll
            for (int n = 0; n < 4; ++n)
                acc[m][n] = __builtin_amdgcn_mfma_f32_16x16x32_f16(af[m], bf[n], acc[m][n], 0, 0, 0);
    }
    float bz[4];
#pragma unroll
    for (int n = 0; n < 4; ++n) bz[n] = bias[bn * 128 + wc * 64 + n * 16 + lr];
    const int lq = l >> 4;
#pragma unroll
    for (int m = 0; m < 4; ++m)
#pragma unroll
        for (int n = 0; n < 4; ++n)
#pragma unroll
            for (int e = 0; e < 4; ++e) {
                int row = bm * 128 + wr * 64 + m * 16 + lq * 4 + e;
                int col = bn * 128 + wc * 64 + n * 16 + lr;
                C[(size_t)row * 512 + col] = (f16)(acc[m][n][e] + bz[n]);
            }
}

// ---------------- persistent recurrence: 512 threads, 224 W-dwords in regs ----------------
#define FOR_Q(M, c, r) M(c, r, 0) M(c, r, 1) M(c, r, 2) M(c, r, 3)
#define FOR_R(M, c) FOR_Q(M, c, 0) FOR_Q(M, c, 1) FOR_Q(M, c, 2) FOR_Q(M, c, 3) \
                    FOR_Q(M, c, 4) FOR_Q(M, c, 5) FOR_Q(M, c, 6) FOR_Q(M, c, 7)
#define FOR_ALL(M) FOR_R(M, 0) FOR_R(M, 1) FOR_R(M, 2) FOR_R(M, 3) \
                   FOR_R(M, 4) FOR_R(M, 5) FOR_R(M, 6)

#define DECLW(c, r, q) uint32_t W_##c##_##r##_##q;
#define LOADW(c, r, q) W_##c##_##r##_##q = wpb[(size_t)(((c)*32 + (r)*4 + (q)) * 512) + tid];
#define DOTQ(c, r, q) a##r = fdot2u(W_##c##_##r##_##q, hq##q, a##r);

#define CHUNK(c)                                                   \
    {                                                              \
        uint4 hv = *(const uint4*)(hrow + (c) * 4);                \
        uint32_t hq0 = hv.x, hq1 = hv.y, hq2 = hv.z, hq3 = hv.w;   \
        FOR_R(DOTQ, c)                                             \
    }

#define LROW(r)                                                    \
    {                                                              \
        uint4 wv = *(const uint4*)&wlds[((r) * 512 + tid) * 4];    \
        a##r = fdot2u(wv.x, hq0, a##r);                            \
        a##r = fdot2u(wv.y, hq1, a##r);                            \
        a##r = fdot2u(wv.z, hq2, a##r);                            \
        a##r = fdot2u(wv.w, hq3, a##r);                            \
    }

#define CHUNKL                                                     \
    {                                                              \
        uint4 hv = *(const uint4*)(hrow + 7 * 4);                  \
        uint32_t hq0 = hv.x, hq1 = hv.y, hq2 = hv.z, hq3 = hv.w;   \
        LROW(0) LROW(1) LROW(2) LROW(3)                            \
        LROW(4) LROW(5) LROW(6) LROW(7)                            \
    }

__global__ __launch_bounds__(512)
__attribute__((amdgpu_waves_per_eu(2, 2)))
void rnn_kernel(const f16* __restrict__ xp, const uint32_t* __restrict__ wpb,
                f16* __restrict__ hout, int store_all) {
    const int b = blockIdx.x;
    const int tid = threadIdx.x;
    const int kg = tid >> 6;   // 0..7, wave-uniform
    const int jq = tid & 63;
    __shared__ alignas(16) f16 hbuf[2][512];
    __shared__ float partA[8 * 256];   // r in [0,4): [kg][jq*4 + r]
    __shared__ float partB[8 * 256];   // r in [4,8)
    __shared__ uint32_t wlds[8 * 512 * 4];   // 64 KB: [r][tid][q]

    FOR_ALL(DECLW)
    FOR_ALL(LOADW)
#pragma unroll
    for (int i = 0; i < 8; ++i) {
        uint4 v = *(const uint4*)&wpb[(size_t)224 * 512 + (size_t)(i * 512 + tid) * 4];
        *(uint4*)&wlds[(i * 512 + tid) * 4] = v;
    }
    hbuf[0][tid] = (f16)0.f;
    __syncthreads();

    const f16* xprow = xp + (size_t)b * 512 * 512;
    f16* houtb = hout + (store_all ? (size_t)b * 512 * 512 : (size_t)b * 512);
    const int jq8 = tid >> 3, r8 = tid & 7;
    const float* pbase = (r8 < 4) ? partA : partB;
    const int pcol = jq8 * 4 + (r8 & 3);

    int p = 0;
    for (int t = 0; t < 512; ++t) {
        float xpv = (float)xprow[(size_t)t * 512 + tid];  // issued early, used after barrier

        float a0 = 0.f, a1 = 0.f, a2 = 0.f, a3 = 0.f;
        float a4 = 0.f, a5 = 0.f, a6 = 0.f, a7 = 0.f;
        const uint32_t* hrow = (const uint32_t*)&hbuf[p][kg * 64];  // wave-uniform broadcast
        CHUNK(0) CHUNK(1) CHUNK(2) CHUNK(3) CHUNK(4) CHUNK(5) CHUNK(6)
        CHUNKL

        *(float4*)&partA[kg * 256 + jq * 4] = make_float4(a0, a1, a2, a3);
        *(float4*)&partB[kg * 256 + jq * 4] = make_float4(a4, a5, a6, a7);
        __syncthreads();
        {
            float s = xpv;
#pragma unroll
            for (int g = 0; g < 8; ++g) s += pbase[g * 256 + pcol];
            float e = __expf(2.0f * s);
            float hn = 1.0f - 2.0f / (1.0f + e);
            f16 hh = (f16)hn;
            hbuf[p ^ 1][tid] = hh;
            if (store_all) houtb[(size_t)t * 512 + tid] = hh;
            else if (t == 511) houtb[tid] = hh;
        }
        __syncthreads();
        p ^= 1;
    }
}

// ---------------- final FC ----------------
__global__ __launch_bounds__(512) void fc_kernel(const f16* __restrict__ h1,
                                                 const float* __restrict__ Wfc,
                                                 const float* __restrict__ bfc,
                                                 float* __restrict__ out) {
    int b = blockIdx.x, tid = threadIdx.x;
    __shared__ float red[8];
    float v = (float)h1[(size_t)b * 512 + tid] * Wfc[tid];
#pragma unroll
    for (int off = 32; off > 0; off >>= 1) v += __shfl_down(v, off, 64);
    if ((tid & 63) == 0) red[tid >> 6] = v;
    __syncthreads();
    if (tid == 0) {
        float s = bfc[0];
#pragma unroll
        for (int g = 0; g < 8; ++g) s += red[g];
        out[b] = s;
    }
}

extern "C" void kernel_launch(void* const* d_in, const int* in_sizes, int n_in,
                              void* d_out, int out_size, void* d_ws, size_t ws_size,
                              hipStream_t stream) {
    const float* x    = (const float*)d_in[0];
    const float* Wih0 = (const float*)d_in[1];
    const float* Whh0 = (const float*)d_in[2];
    const float* bih0 = (const float*)d_in[3];
    const float* bhh0 = (const float*)d_in[4];
    const float* Wih1 = (const float*)d_in[5];
    const float* Whh1 = (const float*)d_in[6];
    const float* bih1 = (const float*)d_in[7];
    const float* bhh1 = (const float*)d_in[8];
    const float* Wfc  = (const float*)d_in[9];
    const float* bfc  = (const float*)d_in[10];
    float* out = (float*)d_out;

    char* ws = (char*)d_ws;
    size_t off = 0;
    auto alloc = [&](size_t bytes) -> void* {
        void* p = ws + off;
        off += (bytes + 255) & ~(size_t)255;
        return p;
    };
    const size_t MTD = (size_t)64 * 512 * 512;
    f16* x16    = (f16*)alloc(MTD * 2);
    f16* h016   = (f16*)alloc(MTD * 2);
    f16* xpb    = (f16*)alloc(MTD * 2);
    f16* wih016 = (f16*)alloc((size_t)512 * 512 * 2);
    f16* wih116 = (f16*)alloc((size_t)512 * 512 * 2);
    uint32_t* wp0 = (uint32_t*)alloc((size_t)131072 * 4);
    uint32_t* wp1 = (uint32_t*)alloc((size_t)131072 * 4);
    float* bs0 = (float*)alloc(512 * 4);
    float* bs1 = (float*)alloc(512 * 4);
    f16* h1last = (f16*)alloc((size_t)64 * 512 * 2);

    // prep
    cvt_kernel<<<2048, 256, 0, stream>>>(x, x16, (int)(MTD / 4));
    cvt_kernel<<<256, 256, 0, stream>>>(Wih0, wih016, 512 * 512 / 4);
    cvt_kernel<<<256, 256, 0, stream>>>(Wih1, wih116, 512 * 512 / 4);
    bsum_kernel<<<1, 512, 0, stream>>>(bih0, bhh0, bs0);
    bsum_kernel<<<1, 512, 0, stream>>>(bih1, bhh1, bs1);
    pack_whh<<<512, 256, 0, stream>>>(Whh0, wp0);
    pack_whh<<<512, 256, 0, stream>>>(Whh1, wp1);

    // layer 0
    gemm_xp<<<1024, 256, 0, stream>>>(x16, wih016, bs0, xpb);
    rnn_kernel<<<64, 512, 0, stream>>>(xpb, wp0, h016, 1);
    // layer 1
    gemm_xp<<<1024, 256, 0, stream>>>(h016, wih116, bs1, xpb);
    rnn_kernel<<<64, 512, 0, stream>>>(xpb, wp1, h1last, 0);
    // head
    fc_kernel<<<64, 512, 0, stream>>>(h1last, Wfc, bfc, out);
}